// Round 8
// baseline (155.882 us; speedup 1.0000x reference)
//
#include <hip/hip_runtime.h>

#define N_TOK 4096
#define NH    4

typedef __attribute__((ext_vector_type(8))) short bf16x8;
typedef __attribute__((ext_vector_type(4))) short bf16x4;
typedef __attribute__((ext_vector_type(4))) float f32x4;

static constexpr float SCALE   = 0.17677669529663687f;  // 32^-0.5
static constexpr float QSCALE  = 0.25503632254435463f;  // SCALE * log2(e)
static constexpr float LAMBDA_ = 0.1f;
#define PSTRIDE 2112   // floats per (h,qt32,ks) partial record

__device__ __forceinline__ unsigned short bf_rne(float f) {
    unsigned u = __float_as_uint(f);
    u += 0x7FFF + ((u >> 16) & 1);
    return (unsigned short)(u >> 16);
}

// ---------------------------------------------------------------------------
// Kernel 1: qkv projection via MFMA with fused prep_w (verbatim R6, verified).
// ---------------------------------------------------------------------------
__global__ __launch_bounds__(256) void qkv_kernel(
    const float* __restrict__ x, const float* __restrict__ wsrc,
    unsigned short* __restrict__ qA, unsigned short* __restrict__ kB,
    unsigned short* __restrict__ vT)
{
    __shared__ __align__(16) float xf[16][132];
    __shared__ __align__(16) unsigned short xbh[16 * 136];
    __shared__ __align__(16) unsigned short xbl[16 * 136];
    __shared__ __align__(16) unsigned short qsh[2][16][64];
    __shared__ __align__(16) unsigned short ksh[2][16][64];
    __shared__ __align__(16) unsigned short vsh[2][32][16];

    const int t  = threadIdx.x;
    const int tg = blockIdx.x >> 1;
    const int rh = blockIdx.x & 1;            // row half: heads {2rh, 2rh+1}
    const int n0 = tg * 16;
    const int nh = n0 >> 8, nw = (n0 >> 4) & 15;
    const int xbase = nh * 2048 + nw * 64;

    #pragma unroll
    for (int k = 0; k < 4; ++k) {
        int idx = t + k * 256;                // 0..1023
        int pair = idx & 7, ch = idx >> 3;
        float4 f4 = *(const float4*)&x[(size_t)ch * 32768 + xbase + pair * 4];
        xf[pair * 2][ch]     = f4.x;
        xf[pair * 2 + 1][ch] = f4.z;
    }
    __syncthreads();
    #pragma unroll
    for (int k = 0; k < 8; ++k) {
        int idx = t + k * 256;
        int tok = idx & 15, ch = idx >> 4;
        float f = xf[tok][ch];
        unsigned u = __float_as_uint(f);
        float lo = f - __uint_as_float(u & 0xFFFF0000u);
        xbh[tok * 136 + ch] = (unsigned short)(u >> 16);
        xbl[tok * 136 + ch] = (unsigned short)(__float_as_uint(lo) >> 16);
    }
    __syncthreads();

    const int lane = t & 63;
    const int m    = lane & 15;
    const int quad = lane >> 4;
    const int w    = t >> 6;

    bf16x8 Bh[4], Bl[4];
    #pragma unroll
    for (int s = 0; s < 4; ++s) {
        Bh[s] = *(const bf16x8*)&xbh[m * 136 + s * 32 + quad * 8];
        Bl[s] = *(const bf16x8*)&xbl[m * 136 + s * 32 + quad * 8];
    }

    #pragma unroll
    for (int rt = 0; rt < 3; ++rt) {
        const int R0 = rh * 192 + w * 48 + rt * 16;
        const int row = R0 + m;
        const int rr_row = row % 96;
        const float sc = (rr_row < 32) ? QSCALE : 1.0f;
        const float* wp = wsrc + (size_t)row * 128;
        bf16x8 Ah[4], Al[4];
        #pragma unroll
        for (int s = 0; s < 4; ++s) {
            float4 f0 = *(const float4*)(wp + s * 32 + quad * 8);
            float4 f1 = *(const float4*)(wp + s * 32 + quad * 8 + 4);
            float fv[8] = {f0.x, f0.y, f0.z, f0.w, f1.x, f1.y, f1.z, f1.w};
            #pragma unroll
            for (int j = 0; j < 8; ++j) {
                float f = fv[j] * sc;
                unsigned u = __float_as_uint(f);
                float lo = f - __uint_as_float(u & 0xFFFF0000u);
                Ah[s][j] = (short)(unsigned short)(u >> 16);
                Al[s][j] = (short)(unsigned short)(__float_as_uint(lo) >> 16);
            }
        }
        f32x4 C = {0, 0, 0, 0};
        #pragma unroll
        for (int s = 0; s < 4; ++s) {
            C = __builtin_amdgcn_mfma_f32_16x16x32_bf16(Ah[s], Bh[s], C, 0, 0, 0);
            C = __builtin_amdgcn_mfma_f32_16x16x32_bf16(Al[s], Bh[s], C, 0, 0, 0);
            C = __builtin_amdgcn_mfma_f32_16x16x32_bf16(Ah[s], Bl[s], C, 0, 0, 0);
        }
        #pragma unroll
        for (int i = 0; i < 4; ++i) {
            int R  = R0 + quad * 4 + i;
            int hh = R / 96;
            int rr = R - hh * 96;
            int hl = hh & 1;
            float f = C[i];
            if (rr < 64) {
                unsigned u = __float_as_uint(f);
                float lo = f - __uint_as_float(u & 0xFFFF0000u);
                unsigned short hi16 = (unsigned short)(u >> 16);
                unsigned short lo16 = (unsigned short)(__float_as_uint(lo) >> 16);
                int part = (rr & 31) >> 4, d = rr & 15;
                if (rr < 32) {
                    qsh[hl][m][part * 32 + d]      = hi16;
                    qsh[hl][m][part * 32 + d + 16] = lo16;
                } else {
                    ksh[hl][m][part * 32 + d]      = hi16;
                    ksh[hl][m][part * 32 + d + 16] = lo16;
                }
            } else {
                vsh[hl][rr - 64][m] = bf_rne(f);
            }
        }
    }
    __syncthreads();

    {   // qA/kB: 32 records (2 heads x 16 tok) x 8 granules of 16B
        int rec = t >> 3, ch8 = t & 7;
        int hl  = rec >> 4, i = rec & 15;
        int hh  = rh * 2 + hl;
        size_t base = ((size_t)hh * N_TOK + n0 + i) * 64 + ch8 * 8;
        *(uint4*)(qA + base) = *(const uint4*)&qsh[hl][i][ch8 * 8];
        *(uint4*)(kB + base) = *(const uint4*)&ksh[hl][i][ch8 * 8];
    }
    if (t < 128) {  // vT granule-tiled: [h][kb][dim][8]
        int hl = t >> 6, d = (t >> 1) & 31, half = t & 1;
        int hh = rh * 2 + hl;
        int kb = (n0 >> 3) + half;
        *(uint4*)(vT + (size_t)hh * 131072 + kb * 256 + d * 8) =
            *(const uint4*)&vsh[hl][d][half * 8];
    }
}

// ---------------------------------------------------------------------------
// Kernel 2: MFMA flash diff-attention v12 — BARRIER-FREE main loop.
// Identical per-wave FP program to the verified v7 (R5): the LDS K/V staging
// was a pure permutation of kB/vT, so each lane's fragment is loaded DIRECTLY
// from global memory (same bytes -> same fragments -> bit-exact):
//   LDS read granule p = quad^(ml&7) held source granule quad
//   => K frag = kt + ml*64 + quad*8 (16B);  V region was an identity copy.
// K/V (5 MB) is L2-resident; the per-tile 12 KB is L1-shared by the block's
// 4 waves. No kv_sh, no stage, NO in-loop __syncthreads: waves free-run at
// arbitrary phases (removes the lockstep stall measured as ~50% idle).
// Obuf kh-merge (2-contributor commutative atomics), epilogue, parts layout:
// verbatim R5. Grid 1024 x 256thr = 4 blocks/CU, 16 waves/CU.
// ---------------------------------------------------------------------------
__global__ __launch_bounds__(256, 4) void flash_kernel(
    const unsigned short* __restrict__ qA, const unsigned short* __restrict__ kB,
    const unsigned short* __restrict__ vT, float* __restrict__ parts)
{
    __shared__ float Obuf[2][2][16][33];                    // [qt][br][r][d+pad]
    __shared__ float lbuf[2][2][16];

    const int t    = threadIdx.x;
    const int w    = t >> 6;
    const int lane = t & 63;
    const int m    = lane & 15;
    const int quad = lane >> 4;
    const int ks   = blockIdx.x & 1;
    const int qt   = (blockIdx.x >> 1) & 127;
    const int h    = blockIdx.x >> 8;
    const int qtile = w >> 1;                 // 0..1
    const int kh    = w & 1;                  // key half within tile
    const int qbase = qt * 32;

    const unsigned short* kBh = kB + (size_t)h * N_TOK * 64;
    const unsigned short* vTh = vT + (size_t)h * 131072;
    const int key0 = ks * 2048;

    for (int i = t; i < 2112; i += 256) ((float*)Obuf)[i] = 0.f;
    if (t < 64) ((float*)lbuf)[t] = 0.f;
    __syncthreads();   // init before any epilogue atomics (only barrier besides readout)

    const unsigned short* qrec = qA + (size_t)(h * N_TOK + qbase + qtile * 16 + m) * 64;
    const bf16x8 zz = {0,0,0,0,0,0,0,0};
    bf16x8 Bq1h = *(const bf16x8*)(qrec + (quad & 1) * 8);
    bf16x8 Bq2h = *(const bf16x8*)(qrec + 32 + (quad & 1) * 8);
    bf16x8 Bq1l = (quad < 2) ? *(const bf16x8*)(qrec + 16 + quad * 8) : zz;
    bf16x8 Bq2l = (quad < 2) ? *(const bf16x8*)(qrec + 48 + quad * 8) : zz;

    f32x4 O1a = {0,0,0,0}, O1b = {0,0,0,0}, O2a = {0,0,0,0}, O2b = {0,0,0,0};
    float l1 = 0.f, l2 = 0.f;

    const int ml0 = kh * 32 + m, ml1 = ml0 + 16;
    const int kbl0 = kh * 4 + (quad >> 1);
    // direct-global fragment offsets (shorts), per tile add tile*4096 (K) / tile*2048 (V)
    const int ka10 = ml0 * 64 + quad * 8;
    const int ka20 = ml0 * 64 + (4 + quad) * 8;
    const int ka11 = ml1 * 64 + quad * 8;
    const int ka21 = ml1 * 64 + (4 + quad) * 8;
    const int vo00 = (kbl0 * 32 + m) * 8 + (quad & 1) * 4;
    const int vo10 = (kbl0 * 32 + 16 + m) * 8 + (quad & 1) * 4;
    const int vo01 = vo00 + 512;
    const int vo11 = vo10 + 512;

    const unsigned short* kt = kBh + (size_t)key0 * 64;
    const unsigned short* vt = vTh + (size_t)(key0 >> 3) * 256;

    for (int tile = 0; tile < 32; ++tile, kt += 4096, vt += 2048) {
        bf16x8 K1_0 = *(const bf16x8*)(kt + ka10);
        bf16x8 K2_0 = *(const bf16x8*)(kt + ka20);
        bf16x8 K1_1 = *(const bf16x8*)(kt + ka11);
        bf16x8 K2_1 = *(const bf16x8*)(kt + ka21);
        bf16x4 V00 = *(const bf16x4*)(vt + vo00);
        bf16x4 V10 = *(const bf16x4*)(vt + vo10);
        bf16x4 V01 = *(const bf16x4*)(vt + vo01);
        bf16x4 V11 = *(const bf16x4*)(vt + vo11);

        __builtin_amdgcn_s_setprio(1);
        f32x4 sA1 = {0,0,0,0}, sA2 = {0,0,0,0};
        f32x4 sB1 = {0,0,0,0}, sB2 = {0,0,0,0};
        sA1 = __builtin_amdgcn_mfma_f32_16x16x32_bf16(K1_0, Bq1h, sA1, 0, 0, 0);
        sB1 = __builtin_amdgcn_mfma_f32_16x16x32_bf16(K1_1, Bq1h, sB1, 0, 0, 0);
        sA1 = __builtin_amdgcn_mfma_f32_16x16x32_bf16(K1_0, Bq1l, sA1, 0, 0, 0);
        sB1 = __builtin_amdgcn_mfma_f32_16x16x32_bf16(K1_1, Bq1l, sB1, 0, 0, 0);
        sA2 = __builtin_amdgcn_mfma_f32_16x16x32_bf16(K2_0, Bq2h, sA2, 0, 0, 0);
        sB2 = __builtin_amdgcn_mfma_f32_16x16x32_bf16(K2_1, Bq2h, sB2, 0, 0, 0);
        sA2 = __builtin_amdgcn_mfma_f32_16x16x32_bf16(K2_0, Bq2l, sA2, 0, 0, 0);
        sB2 = __builtin_amdgcn_mfma_f32_16x16x32_bf16(K2_1, Bq2l, sB2, 0, 0, 0);

        float pa0 = __builtin_amdgcn_exp2f(sA1[0]), pa1 = __builtin_amdgcn_exp2f(sA1[1]);
        float pa2 = __builtin_amdgcn_exp2f(sA1[2]), pa3 = __builtin_amdgcn_exp2f(sA1[3]);
        float pb0 = __builtin_amdgcn_exp2f(sB1[0]), pb1 = __builtin_amdgcn_exp2f(sB1[1]);
        float pb2 = __builtin_amdgcn_exp2f(sB1[2]), pb3 = __builtin_amdgcn_exp2f(sB1[3]);
        float qa0 = __builtin_amdgcn_exp2f(sA2[0]), qa1 = __builtin_amdgcn_exp2f(sA2[1]);
        float qa2 = __builtin_amdgcn_exp2f(sA2[2]), qa3 = __builtin_amdgcn_exp2f(sA2[3]);
        float qb0 = __builtin_amdgcn_exp2f(sB2[0]), qb1 = __builtin_amdgcn_exp2f(sB2[1]);
        float qb2 = __builtin_amdgcn_exp2f(sB2[2]), qb3 = __builtin_amdgcn_exp2f(sB2[3]);
        l1 += (pa0 + pa1) + (pa2 + pa3) + (pb0 + pb1) + (pb2 + pb3);
        l2 += (qa0 + qa1) + (qa2 + qa3) + (qb0 + qb1) + (qb2 + qb3);
        union { unsigned u[2]; bf16x4 v; } cA1, cB1, cA2, cB2;
        cA1.u[0] = __builtin_amdgcn_perm(__float_as_uint(pa1), __float_as_uint(pa0), 0x07060302u);
        cA1.u[1] = __builtin_amdgcn_perm(__float_as_uint(pa3), __float_as_uint(pa2), 0x07060302u);
        cB1.u[0] = __builtin_amdgcn_perm(__float_as_uint(pb1), __float_as_uint(pb0), 0x07060302u);
        cB1.u[1] = __builtin_amdgcn_perm(__float_as_uint(pb3), __float_as_uint(pb2), 0x07060302u);
        cA2.u[0] = __builtin_amdgcn_perm(__float_as_uint(qa1), __float_as_uint(qa0), 0x07060302u);
        cA2.u[1] = __builtin_amdgcn_perm(__float_as_uint(qa3), __float_as_uint(qa2), 0x07060302u);
        cB2.u[0] = __builtin_amdgcn_perm(__float_as_uint(qb1), __float_as_uint(qb0), 0x07060302u);
        cB2.u[1] = __builtin_amdgcn_perm(__float_as_uint(qb3), __float_as_uint(qb2), 0x07060302u);

        O1a = __builtin_amdgcn_mfma_f32_16x16x16bf16_1k(cA1.v, V00, O1a, 0, 0, 0);
        O1b = __builtin_amdgcn_mfma_f32_16x16x16bf16_1k(cA1.v, V10, O1b, 0, 0, 0);
        O2a = __builtin_amdgcn_mfma_f32_16x16x16bf16_1k(cA2.v, V00, O2a, 0, 0, 0);
        O2b = __builtin_amdgcn_mfma_f32_16x16x16bf16_1k(cA2.v, V10, O2b, 0, 0, 0);
        O1a = __builtin_amdgcn_mfma_f32_16x16x16bf16_1k(cB1.v, V01, O1a, 0, 0, 0);
        O1b = __builtin_amdgcn_mfma_f32_16x16x16bf16_1k(cB1.v, V11, O1b, 0, 0, 0);
        O2a = __builtin_amdgcn_mfma_f32_16x16x16bf16_1k(cB2.v, V01, O2a, 0, 0, 0);
        O2b = __builtin_amdgcn_mfma_f32_16x16x16bf16_1k(cB2.v, V11, O2b, 0, 0, 0);
        __builtin_amdgcn_s_setprio(0);
    }

    l1 += __shfl_xor(l1, 16, 64); l1 += __shfl_xor(l1, 32, 64);
    l2 += __shfl_xor(l2, 16, 64); l2 += __shfl_xor(l2, 32, 64);
    if (lane < 16) {
        atomicAdd(&lbuf[qtile][0][m], l1);
        atomicAdd(&lbuf[qtile][1][m], l2);
    }
    #pragma unroll
    for (int i = 0; i < 4; ++i) {
        int r = quad * 4 + i;
        atomicAdd(&Obuf[qtile][0][r][m],      O1a[i]);
        atomicAdd(&Obuf[qtile][0][r][16 + m], O1b[i]);
        atomicAdd(&Obuf[qtile][1][r][m],      O2a[i]);
        atomicAdd(&Obuf[qtile][1][r][16 + m], O2b[i]);
    }
    __syncthreads();

    float* dst = parts + (size_t)((h * 128 + qt) * 2 + ks) * PSTRIDE;
    for (int i = t; i < 1024; i += 256) {
        int r = i >> 5, d = i & 31;
        int qtl = r >> 4, rl = r & 15;
        dst[i]        = Obuf[qtl][0][rl][d];
        dst[1024 + i] = Obuf[qtl][1][rl][d];
    }
    if (t < 32) {
        int qtl = t >> 4, rl = t & 15;
        dst[2048 + t] = lbuf[qtl][0][rl];
        dst[2080 + t] = lbuf[qtl][1][rl];
    }
}

// ---------------------------------------------------------------------------
// Kernel 3: split-K merge + finalize, float4-vectorized (verbatim R6).
// ---------------------------------------------------------------------------
__global__ __launch_bounds__(256) void merge_kernel(
    const float* __restrict__ parts, float* __restrict__ out)
{
    int idx = blockIdx.x * 256 + threadIdx.x;     // 131072 threads
    int d4 = (idx & 7) * 4;
    int row = idx >> 3;
    int h = row >> 12, n = row & 4095;
    int qt = n >> 5, r = n & 31;
    const float* p0 = parts + (size_t)((h * 128 + qt) * 2) * PSTRIDE;
    const float* p1 = p0 + PSTRIDE;
    float4 a1 = *(const float4*)(p0 + r * 32 + d4);
    float4 b1 = *(const float4*)(p1 + r * 32 + d4);
    float4 a2 = *(const float4*)(p0 + 1024 + r * 32 + d4);
    float4 b2 = *(const float4*)(p1 + 1024 + r * 32 + d4);
    float l1 = p0[2048 + r] + p1[2048 + r];
    float l2 = p0[2080 + r] + p1[2080 + r];
    float4 o;
    o.x = (a1.x + b1.x) / l1 - LAMBDA_ * ((a2.x + b2.x) / l2);
    o.y = (a1.y + b1.y) / l1 - LAMBDA_ * ((a2.y + b2.y) / l2);
    o.z = (a1.z + b1.z) / l1 - LAMBDA_ * ((a2.z + b2.z) / l2);
    o.w = (a1.w + b1.w) / l1 - LAMBDA_ * ((a2.w + b2.w) / l2);
    *(float4*)(out + (size_t)idx * 4) = o;
}

extern "C" void kernel_launch(void* const* d_in, const int* in_sizes, int n_in,
                              void* d_out, int out_size, void* d_ws, size_t ws_size,
                              hipStream_t stream) {
    const float* x = (const float*)d_in[0];   // (1,128,32,32,32)
    const float* w = (const float*)d_in[1];   // (384,128)
    float* out = (float*)d_out;               // [h][n][32] flat

    unsigned short* qA = (unsigned short*)d_ws;               // 2 MB
    unsigned short* kB = qA + (size_t)NH * N_TOK * 64;        // 2 MB
    unsigned short* vT = kB + (size_t)NH * N_TOK * 64;        // 1 MB
    float* parts = (float*)(vT + (size_t)NH * 32 * N_TOK);    // 1024*2112*4B = 8.65 MB

    qkv_kernel<<<512, 256, 0, stream>>>(x, w, qA, kB, vT);
    flash_kernel<<<1024, 256, 0, stream>>>(qA, kB, vT, parts);
    merge_kernel<<<512, 256, 0, stream>>>(parts, out);
}

// Round 9
// 120.508 us; speedup vs baseline: 1.2935x; 1.2935x over previous
//
#include <hip/hip_runtime.h>

#define N_TOK 4096
#define NH    4

typedef __attribute__((ext_vector_type(8))) short bf16x8;
typedef __attribute__((ext_vector_type(4))) short bf16x4;
typedef __attribute__((ext_vector_type(4))) float f32x4;

static constexpr float SCALE   = 0.17677669529663687f;  // 32^-0.5
static constexpr float QSCALE  = 0.25503632254435463f;  // SCALE * log2(e)
static constexpr float LAMBDA_ = 0.1f;
#define PSTRIDE 2112   // floats per (h,qt32,ks) partial record

__device__ __forceinline__ unsigned short bf_rne(float f) {
    unsigned u = __float_as_uint(f);
    u += 0x7FFF + ((u >> 16) & 1);
    return (unsigned short)(u >> 16);
}

// ---------------------------------------------------------------------------
// Kernel 1: qkv projection via MFMA with fused prep_w (verbatim R6 compute).
// kB / vT are now written in FRAGMENT-MAJOR layout per 64-key tile so the
// flash kernel's direct-global fragment loads are lane-contiguous (coalesced):
//   K granule (ml,g) -> chunk f=((ml>>4)&1)*2+(g>>2), kh=ml>>5, lane=(g&3)*16+(ml&15)
//   V granule (kbl,d,h2) -> vf=((kbl>>1)&1)*2+(d>>4), kh=kbl>>2, lane=(((kbl&1)<<1)|h2)*16+(d&15)
// Pure permutation of the same bf16 values -> identical fragments (R8-verified).
// ---------------------------------------------------------------------------
__global__ __launch_bounds__(256) void qkv_kernel(
    const float* __restrict__ x, const float* __restrict__ wsrc,
    unsigned short* __restrict__ qA, unsigned short* __restrict__ kB,
    unsigned short* __restrict__ vT)
{
    __shared__ __align__(16) float xf[16][132];
    __shared__ __align__(16) unsigned short xbh[16 * 136];
    __shared__ __align__(16) unsigned short xbl[16 * 136];
    __shared__ __align__(16) unsigned short qsh[2][16][64];
    __shared__ __align__(16) unsigned short ksh[2][16][64];
    __shared__ __align__(16) unsigned short vsh[2][32][16];

    const int t  = threadIdx.x;
    const int tg = blockIdx.x >> 1;
    const int rh = blockIdx.x & 1;            // row half: heads {2rh, 2rh+1}
    const int n0 = tg * 16;
    const int nh = n0 >> 8, nw = (n0 >> 4) & 15;
    const int xbase = nh * 2048 + nw * 64;

    #pragma unroll
    for (int k = 0; k < 4; ++k) {
        int idx = t + k * 256;                // 0..1023
        int pair = idx & 7, ch = idx >> 3;
        float4 f4 = *(const float4*)&x[(size_t)ch * 32768 + xbase + pair * 4];
        xf[pair * 2][ch]     = f4.x;
        xf[pair * 2 + 1][ch] = f4.z;
    }
    __syncthreads();
    #pragma unroll
    for (int k = 0; k < 8; ++k) {
        int idx = t + k * 256;
        int tok = idx & 15, ch = idx >> 4;
        float f = xf[tok][ch];
        unsigned u = __float_as_uint(f);
        float lo = f - __uint_as_float(u & 0xFFFF0000u);
        xbh[tok * 136 + ch] = (unsigned short)(u >> 16);
        xbl[tok * 136 + ch] = (unsigned short)(__float_as_uint(lo) >> 16);
    }
    __syncthreads();

    const int lane = t & 63;
    const int m    = lane & 15;
    const int quad = lane >> 4;
    const int w    = t >> 6;

    bf16x8 Bh[4], Bl[4];
    #pragma unroll
    for (int s = 0; s < 4; ++s) {
        Bh[s] = *(const bf16x8*)&xbh[m * 136 + s * 32 + quad * 8];
        Bl[s] = *(const bf16x8*)&xbl[m * 136 + s * 32 + quad * 8];
    }

    #pragma unroll
    for (int rt = 0; rt < 3; ++rt) {
        const int R0 = rh * 192 + w * 48 + rt * 16;
        const int row = R0 + m;
        const int rr_row = row % 96;
        const float sc = (rr_row < 32) ? QSCALE : 1.0f;
        const float* wp = wsrc + (size_t)row * 128;
        bf16x8 Ah[4], Al[4];
        #pragma unroll
        for (int s = 0; s < 4; ++s) {
            float4 f0 = *(const float4*)(wp + s * 32 + quad * 8);
            float4 f1 = *(const float4*)(wp + s * 32 + quad * 8 + 4);
            float fv[8] = {f0.x, f0.y, f0.z, f0.w, f1.x, f1.y, f1.z, f1.w};
            #pragma unroll
            for (int j = 0; j < 8; ++j) {
                float f = fv[j] * sc;
                unsigned u = __float_as_uint(f);
                float lo = f - __uint_as_float(u & 0xFFFF0000u);
                Ah[s][j] = (short)(unsigned short)(u >> 16);
                Al[s][j] = (short)(unsigned short)(__float_as_uint(lo) >> 16);
            }
        }
        f32x4 C = {0, 0, 0, 0};
        #pragma unroll
        for (int s = 0; s < 4; ++s) {
            C = __builtin_amdgcn_mfma_f32_16x16x32_bf16(Ah[s], Bh[s], C, 0, 0, 0);
            C = __builtin_amdgcn_mfma_f32_16x16x32_bf16(Al[s], Bh[s], C, 0, 0, 0);
            C = __builtin_amdgcn_mfma_f32_16x16x32_bf16(Ah[s], Bl[s], C, 0, 0, 0);
        }
        #pragma unroll
        for (int i = 0; i < 4; ++i) {
            int R  = R0 + quad * 4 + i;
            int hh = R / 96;
            int rr = R - hh * 96;
            int hl = hh & 1;
            float f = C[i];
            if (rr < 64) {
                unsigned u = __float_as_uint(f);
                float lo = f - __uint_as_float(u & 0xFFFF0000u);
                unsigned short hi16 = (unsigned short)(u >> 16);
                unsigned short lo16 = (unsigned short)(__float_as_uint(lo) >> 16);
                int part = (rr & 31) >> 4, d = rr & 15;
                if (rr < 32) {
                    qsh[hl][m][part * 32 + d]      = hi16;
                    qsh[hl][m][part * 32 + d + 16] = lo16;
                } else {
                    ksh[hl][m][part * 32 + d]      = hi16;
                    ksh[hl][m][part * 32 + d + 16] = lo16;
                }
            } else {
                vsh[hl][rr - 64][m] = bf_rne(f);
            }
        }
    }
    __syncthreads();

    {   // qA: old per-token layout (unchanged). kB: fragment-major layout.
        int rec = t >> 3, g = t & 7;
        int hl  = rec >> 4, i = rec & 15;
        int hh  = rh * 2 + hl;
        int n   = n0 + i;
        size_t qbase = ((size_t)hh * N_TOK + n) * 64 + g * 8;
        *(uint4*)(qA + qbase) = *(const uint4*)&qsh[hl][i][g * 8];

        int tile = n >> 6, ml = n & 63;
        int kh2 = ml >> 5, mlb = (ml >> 4) & 1, mm = ml & 15;
        int f = mlb * 2 + (g >> 2), qd = g & 3;
        size_t koff = (size_t)hh * 262144 + (size_t)tile * 4096
                    + ((kh2 * 4 + f) * 64 + qd * 16 + mm) * 8;
        *(uint4*)(kB + koff) = *(const uint4*)&ksh[hl][i][g * 8];
    }
    if (t < 128) {  // vT fragment-major: two 8B granule stores per thread
        int hl = t >> 6, d = (t >> 1) & 31, half = t & 1;
        int hh = rh * 2 + hl;
        int kb = (n0 >> 3) + half;
        int tile = kb >> 3, kbl = kb & 7;
        int kh2 = kbl >> 2;
        int vf  = ((kbl >> 1) & 1) * 2 + (d >> 4);
        int mm  = d & 15;
        size_t vbase = (size_t)hh * 131072 + (size_t)tile * 2048 + (kh2 * 4 + vf) * 256;
        int q0 = (kbl & 1) << 1;
        *(uint2*)(vT + vbase + (q0 * 16 + mm) * 4)       = *(const uint2*)&vsh[hl][d][half * 8];
        *(uint2*)(vT + vbase + ((q0 + 1) * 16 + mm) * 4) = *(const uint2*)&vsh[hl][d][half * 8 + 4];
    }
}

// ---------------------------------------------------------------------------
// Kernel 2: MFMA flash diff-attention v13 — barrier-free + coalesced direct
// loads + register double-buffer prefetch.
// Per-wave FP program identical to verified v7/R8 (bit-exact): fragments come
// from the fragment-major kB/vT (same bytes, permuted addresses), loads are
// lane-contiguous (1KB/instr), next tile's 8 fragments are prefetched into a
// second register set while computing the current tile (unrolled x2, static
// reg names). No kv LDS, no in-loop barriers: waves self-pace.
// Obuf kh-merge (2-contributor commutative atomics), epilogue, parts layout:
// verbatim R5. Grid 1024 x 256thr = 4 blocks/CU.
// ---------------------------------------------------------------------------
__global__ __launch_bounds__(256, 4) void flash_kernel(
    const unsigned short* __restrict__ qA, const unsigned short* __restrict__ kB,
    const unsigned short* __restrict__ vT, float* __restrict__ parts)
{
    __shared__ float Obuf[2][2][16][33];                    // [qt][br][r][d+pad]
    __shared__ float lbuf[2][2][16];

    const int t    = threadIdx.x;
    const int w    = t >> 6;
    const int lane = t & 63;
    const int m    = lane & 15;
    const int quad = lane >> 4;
    const int ks   = blockIdx.x & 1;
    const int qt   = (blockIdx.x >> 1) & 127;
    const int h    = blockIdx.x >> 8;
    const int qtile = w >> 1;                 // 0..1
    const int kh    = w & 1;                  // key half within tile
    const int qbase = qt * 32;

    for (int i = t; i < 2112; i += 256) ((float*)Obuf)[i] = 0.f;
    if (t < 64) ((float*)lbuf)[t] = 0.f;
    __syncthreads();   // protect Obuf init (only barrier besides readout)

    const unsigned short* qrec = qA + (size_t)(h * N_TOK + qbase + qtile * 16 + m) * 64;
    const bf16x8 zz = {0,0,0,0,0,0,0,0};
    bf16x8 Bq1h = *(const bf16x8*)(qrec + (quad & 1) * 8);
    bf16x8 Bq2h = *(const bf16x8*)(qrec + 32 + (quad & 1) * 8);
    bf16x8 Bq1l = (quad < 2) ? *(const bf16x8*)(qrec + 16 + quad * 8) : zz;
    bf16x8 Bq2l = (quad < 2) ? *(const bf16x8*)(qrec + 48 + quad * 8) : zz;

    f32x4 O1a = {0,0,0,0}, O1b = {0,0,0,0}, O2a = {0,0,0,0}, O2b = {0,0,0,0};
    float l1 = 0.f, l2 = 0.f;

    // fragment-major bases: K chunk (kh*4+f)*512 shorts, V chunk (kh*4+vf)*256
    const unsigned short* kt = kB + (size_t)h * 262144 + (size_t)ks * 131072;
    const unsigned short* vt = vT + (size_t)h * 131072 + (size_t)ks * 65536;
    const int kcb = kh * 2048 + lane * 8;     // + f*512 + tile*4096
    const int vcb = kh * 1024 + lane * 4;     // + vf*256 + tile*2048

    bf16x8 Ka0, Ka1, Ka2, Ka3, Kb0, Kb1, Kb2, Kb3;
    bf16x4 Va0, Va1, Va2, Va3, Vb0, Vb1, Vb2, Vb3;

#define LOADSET(K0, K1, K2, K3, V0, V1, V2, V3, TILE)                          \
    {                                                                          \
        const unsigned short* kp = kt + (size_t)(TILE) * 4096 + kcb;           \
        const unsigned short* vp = vt + (size_t)(TILE) * 2048 + vcb;           \
        K0 = *(const bf16x8*)(kp);                                             \
        K1 = *(const bf16x8*)(kp + 512);                                       \
        K2 = *(const bf16x8*)(kp + 1024);                                      \
        K3 = *(const bf16x8*)(kp + 1536);                                      \
        V0 = *(const bf16x4*)(vp);                                             \
        V1 = *(const bf16x4*)(vp + 256);                                       \
        V2 = *(const bf16x4*)(vp + 512);                                       \
        V3 = *(const bf16x4*)(vp + 768);                                       \
    }

    auto compute = [&](bf16x8 K1_0, bf16x8 K2_0, bf16x8 K1_1, bf16x8 K2_1,
                       bf16x4 V00, bf16x4 V10, bf16x4 V01, bf16x4 V11) {
        __builtin_amdgcn_s_setprio(1);
        f32x4 sA1 = {0,0,0,0}, sA2 = {0,0,0,0};
        f32x4 sB1 = {0,0,0,0}, sB2 = {0,0,0,0};
        sA1 = __builtin_amdgcn_mfma_f32_16x16x32_bf16(K1_0, Bq1h, sA1, 0, 0, 0);
        sB1 = __builtin_amdgcn_mfma_f32_16x16x32_bf16(K1_1, Bq1h, sB1, 0, 0, 0);
        sA1 = __builtin_amdgcn_mfma_f32_16x16x32_bf16(K1_0, Bq1l, sA1, 0, 0, 0);
        sB1 = __builtin_amdgcn_mfma_f32_16x16x32_bf16(K1_1, Bq1l, sB1, 0, 0, 0);
        sA2 = __builtin_amdgcn_mfma_f32_16x16x32_bf16(K2_0, Bq2h, sA2, 0, 0, 0);
        sB2 = __builtin_amdgcn_mfma_f32_16x16x32_bf16(K2_1, Bq2h, sB2, 0, 0, 0);
        sA2 = __builtin_amdgcn_mfma_f32_16x16x32_bf16(K2_0, Bq2l, sA2, 0, 0, 0);
        sB2 = __builtin_amdgcn_mfma_f32_16x16x32_bf16(K2_1, Bq2l, sB2, 0, 0, 0);

        float pa0 = __builtin_amdgcn_exp2f(sA1[0]), pa1 = __builtin_amdgcn_exp2f(sA1[1]);
        float pa2 = __builtin_amdgcn_exp2f(sA1[2]), pa3 = __builtin_amdgcn_exp2f(sA1[3]);
        float pb0 = __builtin_amdgcn_exp2f(sB1[0]), pb1 = __builtin_amdgcn_exp2f(sB1[1]);
        float pb2 = __builtin_amdgcn_exp2f(sB1[2]), pb3 = __builtin_amdgcn_exp2f(sB1[3]);
        float qa0 = __builtin_amdgcn_exp2f(sA2[0]), qa1 = __builtin_amdgcn_exp2f(sA2[1]);
        float qa2 = __builtin_amdgcn_exp2f(sA2[2]), qa3 = __builtin_amdgcn_exp2f(sA2[3]);
        float qb0 = __builtin_amdgcn_exp2f(sB2[0]), qb1 = __builtin_amdgcn_exp2f(sB2[1]);
        float qb2 = __builtin_amdgcn_exp2f(sB2[2]), qb3 = __builtin_amdgcn_exp2f(sB2[3]);
        l1 += (pa0 + pa1) + (pa2 + pa3) + (pb0 + pb1) + (pb2 + pb3);
        l2 += (qa0 + qa1) + (qa2 + qa3) + (qb0 + qb1) + (qb2 + qb3);
        union { unsigned u[2]; bf16x4 v; } cA1, cB1, cA2, cB2;
        cA1.u[0] = __builtin_amdgcn_perm(__float_as_uint(pa1), __float_as_uint(pa0), 0x07060302u);
        cA1.u[1] = __builtin_amdgcn_perm(__float_as_uint(pa3), __float_as_uint(pa2), 0x07060302u);
        cB1.u[0] = __builtin_amdgcn_perm(__float_as_uint(pb1), __float_as_uint(pb0), 0x07060302u);
        cB1.u[1] = __builtin_amdgcn_perm(__float_as_uint(pb3), __float_as_uint(pb2), 0x07060302u);
        cA2.u[0] = __builtin_amdgcn_perm(__float_as_uint(qa1), __float_as_uint(qa0), 0x07060302u);
        cA2.u[1] = __builtin_amdgcn_perm(__float_as_uint(qa3), __float_as_uint(qa2), 0x07060302u);
        cB2.u[0] = __builtin_amdgcn_perm(__float_as_uint(qb1), __float_as_uint(qb0), 0x07060302u);
        cB2.u[1] = __builtin_amdgcn_perm(__float_as_uint(qb3), __float_as_uint(qb2), 0x07060302u);

        O1a = __builtin_amdgcn_mfma_f32_16x16x16bf16_1k(cA1.v, V00, O1a, 0, 0, 0);
        O1b = __builtin_amdgcn_mfma_f32_16x16x16bf16_1k(cA1.v, V10, O1b, 0, 0, 0);
        O2a = __builtin_amdgcn_mfma_f32_16x16x16bf16_1k(cA2.v, V00, O2a, 0, 0, 0);
        O2b = __builtin_amdgcn_mfma_f32_16x16x16bf16_1k(cA2.v, V10, O2b, 0, 0, 0);
        O1a = __builtin_amdgcn_mfma_f32_16x16x16bf16_1k(cB1.v, V01, O1a, 0, 0, 0);
        O1b = __builtin_amdgcn_mfma_f32_16x16x16bf16_1k(cB1.v, V11, O1b, 0, 0, 0);
        O2a = __builtin_amdgcn_mfma_f32_16x16x16bf16_1k(cB2.v, V01, O2a, 0, 0, 0);
        O2b = __builtin_amdgcn_mfma_f32_16x16x16bf16_1k(cB2.v, V11, O2b, 0, 0, 0);
        __builtin_amdgcn_s_setprio(0);
    };

    LOADSET(Ka0, Ka1, Ka2, Ka3, Va0, Va1, Va2, Va3, 0);
    for (int tile = 0; tile < 32; tile += 2) {
        LOADSET(Kb0, Kb1, Kb2, Kb3, Vb0, Vb1, Vb2, Vb3, tile + 1);
        compute(Ka0, Ka1, Ka2, Ka3, Va0, Va1, Va2, Va3);
        if (tile + 2 < 32)
            LOADSET(Ka0, Ka1, Ka2, Ka3, Va0, Va1, Va2, Va3, tile + 2);
        compute(Kb0, Kb1, Kb2, Kb3, Vb0, Vb1, Vb2, Vb3);
    }
#undef LOADSET

    l1 += __shfl_xor(l1, 16, 64); l1 += __shfl_xor(l1, 32, 64);
    l2 += __shfl_xor(l2, 16, 64); l2 += __shfl_xor(l2, 32, 64);
    if (lane < 16) {
        atomicAdd(&lbuf[qtile][0][m], l1);
        atomicAdd(&lbuf[qtile][1][m], l2);
    }
    #pragma unroll
    for (int i = 0; i < 4; ++i) {
        int r = quad * 4 + i;
        atomicAdd(&Obuf[qtile][0][r][m],      O1a[i]);
        atomicAdd(&Obuf[qtile][0][r][16 + m], O1b[i]);
        atomicAdd(&Obuf[qtile][1][r][m],      O2a[i]);
        atomicAdd(&Obuf[qtile][1][r][16 + m], O2b[i]);
    }
    __syncthreads();

    float* dst = parts + (size_t)((h * 128 + qt) * 2 + ks) * PSTRIDE;
    for (int i = t; i < 1024; i += 256) {
        int r = i >> 5, d = i & 31;
        int qtl = r >> 4, rl = r & 15;
        dst[i]        = Obuf[qtl][0][rl][d];
        dst[1024 + i] = Obuf[qtl][1][rl][d];
    }
    if (t < 32) {
        int qtl = t >> 4, rl = t & 15;
        dst[2048 + t] = lbuf[qtl][0][rl];
        dst[2080 + t] = lbuf[qtl][1][rl];
    }
}

// ---------------------------------------------------------------------------
// Kernel 3: split-K merge + finalize, float4-vectorized (verbatim R6).
// ---------------------------------------------------------------------------
__global__ __launch_bounds__(256) void merge_kernel(
    const float* __restrict__ parts, float* __restrict__ out)
{
    int idx = blockIdx.x * 256 + threadIdx.x;     // 131072 threads
    int d4 = (idx & 7) * 4;
    int row = idx >> 3;
    int h = row >> 12, n = row & 4095;
    int qt = n >> 5, r = n & 31;
    const float* p0 = parts + (size_t)((h * 128 + qt) * 2) * PSTRIDE;
    const float* p1 = p0 + PSTRIDE;
    float4 a1 = *(const float4*)(p0 + r * 32 + d4);
    float4 b1 = *(const float4*)(p1 + r * 32 + d4);
    float4 a2 = *(const float4*)(p0 + 1024 + r * 32 + d4);
    float4 b2 = *(const float4*)(p1 + 1024 + r * 32 + d4);
    float l1 = p0[2048 + r] + p1[2048 + r];
    float l2 = p0[2080 + r] + p1[2080 + r];
    float4 o;
    o.x = (a1.x + b1.x) / l1 - LAMBDA_ * ((a2.x + b2.x) / l2);
    o.y = (a1.y + b1.y) / l1 - LAMBDA_ * ((a2.y + b2.y) / l2);
    o.z = (a1.z + b1.z) / l1 - LAMBDA_ * ((a2.z + b2.z) / l2);
    o.w = (a1.w + b1.w) / l1 - LAMBDA_ * ((a2.w + b2.w) / l2);
    *(float4*)(out + (size_t)idx * 4) = o;
}

extern "C" void kernel_launch(void* const* d_in, const int* in_sizes, int n_in,
                              void* d_out, int out_size, void* d_ws, size_t ws_size,
                              hipStream_t stream) {
    const float* x = (const float*)d_in[0];   // (1,128,32,32,32)
    const float* w = (const float*)d_in[1];   // (384,128)
    float* out = (float*)d_out;               // [h][n][32] flat

    unsigned short* qA = (unsigned short*)d_ws;               // 2 MB
    unsigned short* kB = qA + (size_t)NH * N_TOK * 64;        // 2 MB
    unsigned short* vT = kB + (size_t)NH * N_TOK * 64;        // 1 MB
    float* parts = (float*)(vT + (size_t)NH * 32 * N_TOK);    // 1024*2112*4B = 8.65 MB

    qkv_kernel<<<512, 256, 0, stream>>>(x, w, qA, kB, vT);
    flash_kernel<<<1024, 256, 0, stream>>>(qA, kB, vT, parts);
    merge_kernel<<<512, 256, 0, stream>>>(parts, out);
}